// Round 5
// baseline (67.007 us; speedup 1.0000x reference)
//
#include <hip/hip_runtime.h>

// Block-sparse matrix metadata + dense reconstruction — fused 2-kernel version.
// Grid: X=Y=256 block rows/cols, BH=BW=32, N_BLOCKS=16384.
// Inputs:  d_in[0] = block_mask (bool -> int32, 65536)
//          d_in[1] = data (f32, 16384*32*32)
// Outputs (all FLOAT32, concatenated flat in d_out):
//   [0)           dense 8192x8192                  (67108864)
//   [67108864)    blocks: (col,row) pairs           (32768)
//   [67141632)    cols_a: (col, block_ptr) pairs    (32768)
//   [67174400)    row_start_ends_a                  (257)
//   [67174657)    rows_b: (row, block_ptr_t) pairs  (32768)
//   [67207425)    col_start_ends_b                  (257)

#define GX 256
#define GY 256
#define STRIP 8
#define DENSE_BLOCKS 8192  // 65536 tiles / 8 per block
#define META_BLOCKS 512    // 256 emit-row + 256 emit-col, scheduled FIRST

typedef float f32x4 __attribute__((ext_vector_type(4)));

// K1: 512 blocks x 256 threads.
// blocks [0,256): row b -> row_counts[b] + packed bit row (8 words) via ballot
// blocks [256,512): col (b-256) -> col_counts
__global__ __launch_bounds__(256) void count_kernel(const int* __restrict__ mask,
                                                    int* __restrict__ row_counts,
                                                    int* __restrict__ col_counts,
                                                    unsigned* __restrict__ bits) {
    __shared__ int s[4];
    int b = blockIdx.x, t = threadIdx.x, lane = t & 63, wv = t >> 6;
    int m;
    if (b < GX) m = mask[b * GY + t] ? 1 : 0;
    else        m = mask[t * GY + (b - GX)] ? 1 : 0;
    unsigned long long bl = __ballot(m);
    if (b < GX && lane == 0) {
        bits[b * 8 + wv * 2]     = (unsigned)bl;
        bits[b * 8 + wv * 2 + 1] = (unsigned)(bl >> 32);
    }
    if (lane == 0) s[wv] = __popcll(bl);
    __syncthreads();
    if (t == 0) {
        int tot = s[0] + s[1] + s[2] + s[3];
        if (b < GX) row_counts[b] = tot;
        else        col_counts[b - GX] = tot;
    }
}

// inclusive scan of one value per thread across 256 threads (2 barriers)
__device__ __forceinline__ int block_scan256_incl(int v, int* wsum) {
    int t = threadIdx.x, lane = t & 63, wv = t >> 6;
    __syncthreads();  // protect wsum reuse across calls
    #pragma unroll
    for (int d = 1; d < 64; d <<= 1) {
        int o = __shfl_up(v, d, 64);
        if (lane >= d) v += o;
    }
    if (lane == 63) wsum[wv] = v;
    __syncthreads();
    int s0 = wsum[0], s1 = wsum[1], s2 = wsum[2];
    int add = 0;
    if (wv >= 1) add += s0;
    if (wv >= 2) add += s1;
    if (wv >= 3) add += s2;
    return v + add;
}

// count of set bits at positions < c in an 8-word (256-bit) row; c uniform.
__device__ __forceinline__ int prefix_bits(const unsigned* w8, int c) {
    int full = c >> 5, rem = c & 31;
    int s = 0;
    #pragma unroll
    for (int k = 0; k < 8; ++k)
        if (k < full) s += __popc(w8[k]);
    if (rem) s += __popc(w8[full] & ((1u << rem) - 1u));
    return s;
}

// K2: 8704 blocks x 256 threads.
//  bid < 256           : emit row (blocks / cols_a / row_start_ends)   [first: overlaps]
//  256 <= bid < 512    : emit col (rows_b / col_start_ends)
//  bid >= 512          : dense strip (8 adjacent tiles of one block-row)
__global__ __launch_bounds__(256) void mega_kernel(const float* __restrict__ data,
                                                   const int* __restrict__ mask,
                                                   const int* __restrict__ row_counts,
                                                   const int* __restrict__ col_counts,
                                                   const unsigned* __restrict__ bits,
                                                   float* __restrict__ out) {
    __shared__ float L[32 * 260];
    __shared__ int sc[256];
    __shared__ int wsum[4];

    int bid = blockIdx.x, t = threadIdx.x;

    float* out_blocks = out + 67108864ull;
    float* out_cols_a = out_blocks + 32768;
    float* out_rse    = out_cols_a + 32768;
    float* out_rows_b = out_rse + 257;
    float* out_cse    = out_rows_b + 32768;

    if (bid >= META_BLOCKS) {
        // ---------- dense strip ----------
        int tile0 = (bid - META_BLOCKS) * STRIP;
        int r = tile0 >> 8, c0 = tile0 & 255;

        int incl = block_scan256_incl(row_counts[t], wsum);
        sc[t] = incl;
        __syncthreads();
        int row_start = (r == 0) ? 0 : sc[r - 1];

        unsigned w8[8];
        #pragma unroll
        for (int k = 0; k < 8; ++k) w8[k] = bits[r * 8 + k];  // wave-uniform -> SALU

        int q = t >> 3, p0 = (t & 7) * 4;
        #pragma unroll
        for (int k = 0; k < STRIP; ++k) {
            int c = c0 + k;
            int qq = k * 32 + q;
            f32x4 v = (f32x4)0.0f;
            if ((w8[c >> 5] >> (c & 31)) & 1u) {
                int i = row_start + prefix_bits(w8, c);
                const f32x4* src4 = (const f32x4*)(data + (size_t)i * 1024);
                v = __builtin_nontemporal_load(&src4[t]);
            }
            // XOR swizzle: column bit-3 ^= row bit-3 -> every ds_write is 2-way (free)
            #pragma unroll
            for (int j = 0; j < 4; ++j) {
                int rr = p0 + j;
                int cc = qq ^ (((rr >> 3) & 1) << 3);
                L[rr * 260 + cc] = v[j];
            }
        }
        __syncthreads();

        int u = t & 63, wv = t >> 6;
        f32x4* outv = (f32x4*)out;
        #pragma unroll
        for (int iter = 0; iter < 8; ++iter) {
            int p = iter * 4 + wv;
            int b3 = (iter >> 1) & 1;           // == (p>>3)&1 since wv<4
            const f32x4* lrow = (const f32x4*)&L[p * 260];
            f32x4 f = lrow[u ^ (b3 << 1)];
            __builtin_nontemporal_store(f, &outv[(size_t)(r * 32 + p) * 2048 + c0 * 8 + u]);
        }
    } else if (bid < 256) {
        // ---------- emit rows ----------
        int r = bid;

        int rc = row_counts[t];
        int incl = block_scan256_incl(rc, wsum);
        sc[t] = incl;
        __syncthreads();
        if (r == 0) {
            out_rse[t + 1] = (float)incl;
            if (t == 0) out_rse[0] = 0.0f;
        }
        int row_start = (r == 0) ? 0 : sc[r - 1];

        int m = mask[r * GY + t] ? 1 : 0;
        int mi = block_scan256_incl(m, wsum);
        if (m) {
            int i = row_start + mi - 1;  // row-major rank
            float fc = (float)t;
            *(float2*)&out_blocks[2 * i] = make_float2(fc, (float)r);
            *(float2*)&out_cols_a[2 * i] = make_float2(fc, (float)i);
        }
    } else {
        // ---------- emit cols ----------
        int c = bid - 256;

        int rc = row_counts[t];
        int incl_r = block_scan256_incl(rc, wsum);
        int row_start_own = incl_r - rc;  // exclusive prefix: rank offset of row t

        int incl_c = block_scan256_incl(col_counts[t], wsum);
        sc[t] = incl_c;
        __syncthreads();
        if (c == 0) {
            out_cse[t + 1] = (float)incl_c;
            if (t == 0) out_cse[0] = 0.0f;
        }
        int col_start = (c == 0) ? 0 : sc[c - 1];

        // row t's packed bits; c is uniform
        const unsigned* wp = bits + t * 8;
        int pc = 0;
        for (int k = 0; k < (c >> 5); ++k) pc += __popc(wp[k]);  // uniform trip count
        unsigned wc = wp[c >> 5];
        if (c & 31) pc += __popc(wc & ((1u << (c & 31)) - 1u));
        int m = (wc >> (c & 31)) & 1;
        int i = row_start_own + pc;  // row-major rank of (t, c)

        int ji = block_scan256_incl(m, wsum);
        if (m) {
            int j = col_start + ji - 1;  // col-major rank
            *(float2*)&out_rows_b[2 * j] = make_float2((float)t, (float)i);
        }
    }
}

extern "C" void kernel_launch(void* const* d_in, const int* in_sizes, int n_in,
                              void* d_out, int out_size, void* d_ws, size_t ws_size,
                              hipStream_t stream) {
    const int* mask = (const int*)d_in[0];      // bool -> int32, 65536
    const float* data = (const float*)d_in[1];  // f32, 16777216

    int* ws = (int*)d_ws;
    int* row_counts = ws;                       // 256
    int* col_counts = ws + 256;                 // 256
    unsigned* bits  = (unsigned*)(ws + 512);    // 2048 words (256 rows x 8)

    float* out = (float*)d_out;

    count_kernel<<<512, 256, 0, stream>>>(mask, row_counts, col_counts, bits);
    mega_kernel<<<DENSE_BLOCKS + META_BLOCKS, 256, 0, stream>>>(data, mask, row_counts,
                                                                col_counts, bits, out);
}

// Round 6
// 53.077 us; speedup vs baseline: 1.2625x; 1.2625x over previous
//
#include <hip/hip_runtime.h>

// Block-sparse matrix metadata + dense reconstruction — fused 2-kernel version.
// Round 6 = round 4 (53.1 us) + ONE delta: LDS write-phase XOR swizzle
// (4-way -> 2-way bank conflicts on ds_write, read side adjusted to match).
// NT loads and meta-first ordering from round 5 REVERTED (one of them was -14us).
//
// Grid: X=Y=256 block rows/cols, BH=BW=32, N_BLOCKS=16384.
// Inputs:  d_in[0] = block_mask (bool -> int32, 65536)
//          d_in[1] = data (f32, 16384*32*32)
// Outputs (all FLOAT32, concatenated flat in d_out):
//   [0)           dense 8192x8192                  (67108864)
//   [67108864)    blocks: (col,row) pairs           (32768)
//   [67141632)    cols_a: (col, block_ptr) pairs    (32768)
//   [67174400)    row_start_ends_a                  (257)
//   [67174657)    rows_b: (row, block_ptr_t) pairs  (32768)
//   [67207425)    col_start_ends_b                  (257)

#define GX 256
#define GY 256
#define STRIP 8
#define DENSE_BLOCKS 8192  // 65536 tiles / 8 per block

typedef float f32x4 __attribute__((ext_vector_type(4)));

// K1: 512 blocks x 256 threads.
// blocks [0,256): row b -> row_counts[b] + packed bit row (8 words) via ballot
// blocks [256,512): col (b-256) -> col_counts
__global__ __launch_bounds__(256) void count_kernel(const int* __restrict__ mask,
                                                    int* __restrict__ row_counts,
                                                    int* __restrict__ col_counts,
                                                    unsigned* __restrict__ bits) {
    __shared__ int s[4];
    int b = blockIdx.x, t = threadIdx.x, lane = t & 63, wv = t >> 6;
    int m;
    if (b < GX) m = mask[b * GY + t] ? 1 : 0;
    else        m = mask[t * GY + (b - GX)] ? 1 : 0;
    unsigned long long bl = __ballot(m);
    if (b < GX && lane == 0) {
        bits[b * 8 + wv * 2]     = (unsigned)bl;
        bits[b * 8 + wv * 2 + 1] = (unsigned)(bl >> 32);
    }
    if (lane == 0) s[wv] = __popcll(bl);
    __syncthreads();
    if (t == 0) {
        int tot = s[0] + s[1] + s[2] + s[3];
        if (b < GX) row_counts[b] = tot;
        else        col_counts[b - GX] = tot;
    }
}

// inclusive scan of one value per thread across 256 threads (2 barriers)
__device__ __forceinline__ int block_scan256_incl(int v, int* wsum) {
    int t = threadIdx.x, lane = t & 63, wv = t >> 6;
    __syncthreads();  // protect wsum reuse across calls
    #pragma unroll
    for (int d = 1; d < 64; d <<= 1) {
        int o = __shfl_up(v, d, 64);
        if (lane >= d) v += o;
    }
    if (lane == 63) wsum[wv] = v;
    __syncthreads();
    int s0 = wsum[0], s1 = wsum[1], s2 = wsum[2];
    int add = 0;
    if (wv >= 1) add += s0;
    if (wv >= 2) add += s1;
    if (wv >= 3) add += s2;
    return v + add;
}

// count of set bits at positions < c in an 8-word (256-bit) row; c uniform.
__device__ __forceinline__ int prefix_bits(const unsigned* w8, int c) {
    int full = c >> 5, rem = c & 31;
    int s = 0;
    #pragma unroll
    for (int k = 0; k < 8; ++k)
        if (k < full) s += __popc(w8[k]);
    if (rem) s += __popc(w8[full] & ((1u << rem) - 1u));
    return s;
}

// K2: 8704 blocks x 256 threads.
//  bid < 8192          : dense strip (8 adjacent tiles of one block-row)
//  8192 <= bid < 8448  : emit row (blocks / cols_a / row_start_ends)
//  8448 <= bid         : emit col (rows_b / col_start_ends)
__global__ __launch_bounds__(256) void mega_kernel(const float* __restrict__ data,
                                                   const int* __restrict__ mask,
                                                   const int* __restrict__ row_counts,
                                                   const int* __restrict__ col_counts,
                                                   const unsigned* __restrict__ bits,
                                                   float* __restrict__ out) {
    __shared__ float L[32 * 260];
    __shared__ int sc[256];
    __shared__ int wsum[4];

    int bid = blockIdx.x, t = threadIdx.x;

    float* out_blocks = out + 67108864ull;
    float* out_cols_a = out_blocks + 32768;
    float* out_rse    = out_cols_a + 32768;
    float* out_rows_b = out_rse + 257;
    float* out_cse    = out_rows_b + 32768;

    if (bid < DENSE_BLOCKS) {
        // ---------- dense strip ----------
        int tile0 = bid * STRIP;
        int r = tile0 >> 8, c0 = tile0 & 255;

        int incl = block_scan256_incl(row_counts[t], wsum);
        sc[t] = incl;
        __syncthreads();
        int row_start = (r == 0) ? 0 : sc[r - 1];

        unsigned w8[8];
        #pragma unroll
        for (int k = 0; k < 8; ++k) w8[k] = bits[r * 8 + k];  // wave-uniform -> SALU

        int q = t >> 3, p0 = (t & 7) * 4;
        // XOR swizzle: column bit-3 ^= row bit-3. rr = p0..p0+3 stays in one
        // 8-row group, so cc is shared by all 4 stores (one XOR per strip iter).
        int swz = ((p0 >> 3) & 1) << 3;
        #pragma unroll
        for (int k = 0; k < STRIP; ++k) {
            int c = c0 + k;
            int qq = k * 32 + q;
            f32x4 v = (f32x4)0.0f;
            if ((w8[c >> 5] >> (c & 31)) & 1u) {
                int i = row_start + prefix_bits(w8, c);
                const f32x4* src4 = (const f32x4*)(data + (size_t)i * 1024);
                v = src4[t];
            }
            int cc = qq ^ swz;
            L[(p0 + 0) * 260 + cc] = v[0];
            L[(p0 + 1) * 260 + cc] = v[1];
            L[(p0 + 2) * 260 + cc] = v[2];
            L[(p0 + 3) * 260 + cc] = v[3];
        }
        __syncthreads();

        int u = t & 63, wv = t >> 6;
        f32x4* outv = (f32x4*)out;
        #pragma unroll
        for (int iter = 0; iter < 8; ++iter) {
            int p = iter * 4 + wv;
            int b3 = (iter >> 1) & 1;           // == (p>>3)&1 since wv<4
            const f32x4* lrow = (const f32x4*)&L[p * 260];
            f32x4 f = lrow[u ^ (b3 << 1)];
            __builtin_nontemporal_store(f, &outv[(size_t)(r * 32 + p) * 2048 + c0 * 8 + u]);
        }
    } else if (bid < DENSE_BLOCKS + 256) {
        // ---------- emit rows ----------
        int r = bid - DENSE_BLOCKS;

        int rc = row_counts[t];
        int incl = block_scan256_incl(rc, wsum);
        sc[t] = incl;
        __syncthreads();
        if (r == 0) {
            out_rse[t + 1] = (float)incl;
            if (t == 0) out_rse[0] = 0.0f;
        }
        int row_start = (r == 0) ? 0 : sc[r - 1];

        int m = mask[r * GY + t] ? 1 : 0;
        int mi = block_scan256_incl(m, wsum);
        if (m) {
            int i = row_start + mi - 1;  // row-major rank
            float fc = (float)t;
            *(float2*)&out_blocks[2 * i] = make_float2(fc, (float)r);
            *(float2*)&out_cols_a[2 * i] = make_float2(fc, (float)i);
        }
    } else {
        // ---------- emit cols ----------
        int c = bid - (DENSE_BLOCKS + 256);

        int rc = row_counts[t];
        int incl_r = block_scan256_incl(rc, wsum);
        int row_start_own = incl_r - rc;  // exclusive prefix: rank offset of row t

        int incl_c = block_scan256_incl(col_counts[t], wsum);
        sc[t] = incl_c;
        __syncthreads();
        if (c == 0) {
            out_cse[t + 1] = (float)incl_c;
            if (t == 0) out_cse[0] = 0.0f;
        }
        int col_start = (c == 0) ? 0 : sc[c - 1];

        // row t's packed bits; c is uniform
        const unsigned* wp = bits + t * 8;
        int pc = 0;
        for (int k = 0; k < (c >> 5); ++k) pc += __popc(wp[k]);  // uniform trip count
        unsigned wc = wp[c >> 5];
        if (c & 31) pc += __popc(wc & ((1u << (c & 31)) - 1u));
        int m = (wc >> (c & 31)) & 1;
        int i = row_start_own + pc;  // row-major rank of (t, c)

        int ji = block_scan256_incl(m, wsum);
        if (m) {
            int j = col_start + ji - 1;  // col-major rank
            *(float2*)&out_rows_b[2 * j] = make_float2((float)t, (float)i);
        }
    }
}

extern "C" void kernel_launch(void* const* d_in, const int* in_sizes, int n_in,
                              void* d_out, int out_size, void* d_ws, size_t ws_size,
                              hipStream_t stream) {
    const int* mask = (const int*)d_in[0];      // bool -> int32, 65536
    const float* data = (const float*)d_in[1];  // f32, 16777216

    int* ws = (int*)d_ws;
    int* row_counts = ws;                       // 256
    int* col_counts = ws + 256;                 // 256
    unsigned* bits  = (unsigned*)(ws + 512);    // 2048 words (256 rows x 8)

    float* out = (float*)d_out;

    count_kernel<<<512, 256, 0, stream>>>(mask, row_counts, col_counts, bits);
    mega_kernel<<<DENSE_BLOCKS + 512, 256, 0, stream>>>(data, mask, row_counts,
                                                        col_counts, bits, out);
}